// Round 1
// baseline (223.197 us; speedup 1.0000x reference)
//
#include <hip/hip_runtime.h>
#include <hip/hip_bf16.h>
#include <math.h>

typedef float  f4 __attribute__((ext_vector_type(4)));
typedef short  s8 __attribute__((ext_vector_type(8)));
typedef short  s4 __attribute__((ext_vector_type(4)));
typedef int    i2 __attribute__((ext_vector_type(2)));

#define NV 28
#define NB 32768
#define BN_EPS 1e-5f
#define NSLOT 434   // 28 col-sums + 406 upper-tri Gram products

// ---- workspace layout (float indices unless noted) ----
#define SUM2_OFF   0        // 1792
#define SSQ2_OFF   1792     // 1792
#define BIAS1_OFF  3584     // 1792 -> 5376
#define PART_OFF   9472     // 256*434 -> 120576
#define BF_BASE_F  120640   // bf16 region; byte 482560 (16B aligned)
#define W2B_OFF_S  57344    // short offset of W2 bf16
#define XBF_OFF_S  172032   // short offset of padded bf16 X [32768][32]
// a1 Gram partials (analytic BN2): [28][32][2560 gram + 64 colsum] f32 = 9.4 MB
#define GRAMP_OFF  731136   // float idx == old h2 byte offset 2924544 / 4

// fast gelu via hw exp2/rcp; max abs err ~5e-4
__device__ __forceinline__ float gelu_f(float x) {
    float x2 = x * x;
    float z  = x * __builtin_fmaf(x2, -0.10294324f, -2.3022082f);
    float t  = __builtin_amdgcn_exp2f(z);
    return x * __builtin_amdgcn_rcpf(1.0f + t);
}
// cheap round-to-nearest-even f32->bf16 (finite inputs)
__device__ __forceinline__ unsigned short f2bf(float x) {
    unsigned u = __builtin_bit_cast(unsigned, x);
    return (unsigned short)((u + 0x7fffu + ((u >> 16) & 1u)) >> 16);
}
__device__ __forceinline__ float bf2f(short s) {
    return __builtin_bit_cast(float, ((int)(unsigned short)s) << 16);
}
// pack two f32 -> two bf16 (round-nearest, ties-up) in 3 VALU ops via v_perm
__device__ __forceinline__ int bfpack(float a, float b) {
    unsigned ua = __builtin_bit_cast(unsigned, a) + 0x8000u;
    unsigned ub = __builtin_bit_cast(unsigned, b) + 0x8000u;
    return __builtin_amdgcn_perm(ub, ua, 0x07060302);  // lo16=bf16(a), hi16=bf16(b)
}
// sum across the 16 lanes of a DPP row; all lanes get the total
__device__ __forceinline__ float row16_sum(float v) {
    int x;
    x = __builtin_amdgcn_update_dpp(0, __builtin_bit_cast(int, v), 0xB1, 0xF, 0xF, true);
    v += __builtin_bit_cast(float, x);
    x = __builtin_amdgcn_update_dpp(0, __builtin_bit_cast(int, v), 0x4E, 0xF, 0xF, true);
    v += __builtin_bit_cast(float, x);
    x = __builtin_amdgcn_update_dpp(0, __builtin_bit_cast(int, v), 0x124, 0xF, 0xF, true);
    v += __builtin_bit_cast(float, x);
    x = __builtin_amdgcn_update_dpp(0, __builtin_bit_cast(int, v), 0x128, 0xF, 0xF, true);
    v += __builtin_bit_cast(float, x);
    return v;
}
// sum across a 4-lane quad; all 4 lanes get the total
__device__ __forceinline__ float quad4_sum(float v) {
    int x;
    x = __builtin_amdgcn_update_dpp(0, __builtin_bit_cast(int, v), 0xB1, 0xF, 0xF, true);
    v += __builtin_bit_cast(float, x);
    x = __builtin_amdgcn_update_dpp(0, __builtin_bit_cast(int, v), 0x4E, 0xF, 0xF, true);
    v += __builtin_bit_cast(float, x);
    return v;
}

// ------ X stats partials (upper-tri only) + bf16 pre-conversion of X -----
__global__ __launch_bounds__(256) void k_xstats(const float* __restrict__ X,
                                                float* __restrict__ ws) {
    __shared__ float sx[128 * 28];
    const int tid = threadIdx.x;
    const int rowbase = blockIdx.x * 128;
    {
        const f4* src = (const f4*)(X + (size_t)rowbase * 28);
        f4* dst = (f4*)sx;
        for (int i = tid; i < 128 * 28 / 4; i += 256) dst[i] = src[i];
    }
    __syncthreads();
    // bf16 X, padded to 32 cols (cols 28..31 zero)
    int* xb = (int*)((short*)(ws + BF_BASE_F) + XBF_OFF_S);
    for (int j = tid; j < 128 * 16; j += 256) {
        int row = j >> 4, cc = j & 15;
        float lo = (2 * cc     < 28) ? sx[row * 28 + 2 * cc]     : 0.0f;
        float hi = (2 * cc + 1 < 28) ? sx[row * 28 + 2 * cc + 1] : 0.0f;
        xb[(size_t)(rowbase + row) * 16 + cc] = (int)f2bf(lo) | ((int)f2bf(hi) << 16);
    }
    // slots: 0..27 col sums, 28.. upper-tri products (d<=e)
    for (int s = tid; s < NSLOT; s += 256) {
        float a = 0.0f;
        if (s < 28) {
            for (int r = 0; r < 128; ++r) a += sx[r * 28 + s];
        } else {
            int p = s - 28, d = 0, rem = 28;
            while (p >= rem) { p -= rem; ++d; --rem; }
            int e = d + p;
            for (int r = 0; r < 128; ++r)
                a = __builtin_fmaf(sx[r * 28 + d], sx[r * 28 + e], a);
        }
        ws[PART_OFF + blockIdx.x * NSLOT + s] = a;
    }
}

// ------ fold: reduce partials; sigmoid mask; analytic BN1 -> bf16 weights -
__global__ __launch_bounds__(256) void k_fold1(const float* __restrict__ Wlog,
                                               const float* __restrict__ W1,
                                               const float* __restrict__ g1,
                                               const float* __restrict__ be1,
                                               const float* __restrict__ W2,
                                               float* __restrict__ ws,
                                               float* __restrict__ out_w) {
    __shared__ float sstat[NSLOT];
    __shared__ float mu[28], wrow[28];
    __shared__ float C[784];
    __shared__ float w1e_s[64 * 28];
    const int n = blockIdx.x, t = threadIdx.x;

    for (int s = t; s < NSLOT; s += 256) {
        float a = 0.0f;
#pragma unroll 16
        for (int p = 0; p < 256; ++p) a += ws[PART_OFF + p * NSLOT + s];
        sstat[s] = a;
    }
    __syncthreads();

    if (t < 28) {
        mu[t] = sstat[t] * (1.0f / 32768.0f);
        float w = 1.0f / (1.0f + expf(-Wlog[n * 28 + t]));
        if (t == n) w = 0.0f;
        wrow[t] = w;
        out_w[n * 28 + t] = w;          // second output: adjacency W
    }
    __syncthreads();
    // full covariance from upper-tri Gram: C = G/N - mu mu^T
    for (int i = t; i < 784; i += 256) {
        int d = i / 28, e = i % 28;
        int lo = d < e ? d : e, hi = d < e ? e : d;
        int idx = 28 + lo * 28 - (lo * (lo - 1)) / 2 + (hi - lo);
        C[i] = sstat[idx] * (1.0f / 32768.0f) - mu[d] * mu[e];
    }
    // masked first-layer weights for all 64 units (coalesced W1 reads)
    for (int i = t; i < 1792; i += 256)
        w1e_s[i] = W1[(size_t)n * 1792 + i] * wrow[i % 28];
    __syncthreads();

    const int h = t >> 2, j = t & 3;    // 4 lanes per hidden unit (one quad)
    const float* we = &w1e_s[h * 28];
    float var_p = 0.0f, dot_p = 0.0f;
#pragma unroll
    for (int k = 0; k < 7; ++k) {
        int d = 7 * j + k;
        float inner = 0.0f;
#pragma unroll
        for (int e = 0; e < 28; ++e) inner = __builtin_fmaf(C[d * 28 + e], we[e], inner);
        float wd = we[d];
        var_p = __builtin_fmaf(inner, wd, var_p);
        dot_p = __builtin_fmaf(wd, mu[d], dot_p);
    }
    float var  = quad4_sum(var_p);
    float dotm = quad4_sum(dot_p);
    float scale = g1[n * 64 + h] * rsqrtf(fmaxf(var, 0.0f) + BN_EPS);
    if (j == 0)
        ws[BIAS1_OFF + n * 64 + h] = be1[n * 64 + h] - dotm * scale;  // b1 cancels in BN

    short* bfbase = (short*)(ws + BF_BASE_F);
    {   // folded W1 bf16, padded to 32: lane j packs d in [8j, 8j+8)
        short* w1f = bfbase + (size_t)(n * 64 + h) * 32;
        s8 pk;
#pragma unroll
        for (int k = 0; k < 8; ++k) {
            int d = 8 * j + k;
            pk[k] = (short)f2bf(d < 28 ? we[d] * scale : 0.0f);
        }
        *(s8*)&w1f[8 * j] = pk;
    }
    {   // W2 -> bf16: 16 elements per thread, 16-B stores
        const float* w2src = W2 + (size_t)n * 4096 + t * 16;
        short* w2d = bfbase + W2B_OFF_S + (size_t)n * 4096 + t * 16;
        s8 a, b;
#pragma unroll
        for (int k = 0; k < 8; ++k) a[k] = (short)f2bf(w2src[k]);
#pragma unroll
        for (int k = 0; k < 8; ++k) b[k] = (short)f2bf(w2src[8 + k]);
        *(s8*)&w2d[0] = a;
        *(s8*)&w2d[8] = b;
    }
}

// ------ a1 moment pass: GEMM1+gelu (transposed out) -> Gram + col sums ----
// Per wave: 32-row chunks; swapped-operand MFMA puts a1 as [row][unit m] in
// lanes, packed s4 stores build a transposed LDS tile T[unit][row] (stride 40
// shorts keeps b64 writes / b128 reads at the wave64 minimum beat count).
// 10 upper-tri 16x16 Gram MFMAs accumulate a1^T a1 over K=rows in registers.
__global__ __launch_bounds__(256, 3) void k_agram(float* __restrict__ ws) {
    __shared__ __align__(16) char smem[21504];  // [0,20480) T / gram bufs, [20480,21504) colbuf
    const int n = blockIdx.x >> 5;
    const int blk = blockIdx.x & 31;
    const int tid = threadIdx.x;
    const int wave = tid >> 6;
    const int lane = tid & 63;
    const int m = lane & 15;
    const int q = lane >> 4;

    const short* bfbase = (const short*)(ws + BF_BASE_F);
    const short* w1g = bfbase + (size_t)n * 64 * 32;
    const short* xbf = bfbase + XBF_OFF_S;
    const float* bias1 = ws + BIAS1_OFF + n * 64;

    s8 wgf[4];
    float bv[4];
#pragma unroll
    for (int u = 0; u < 4; ++u) {
        wgf[u] = *(const s8*)&w1g[(16 * u + m) * 32 + 8 * q];
        bv[u]  = bias1[16 * u + m];
    }

    short* T = (short*)(smem + wave * 5120);   // wave-private [64][40] shorts
    f4 gram[10];
#pragma unroll
    for (int p = 0; p < 10; ++p) gram[p] = (f4){0.f, 0.f, 0.f, 0.f};
    float csum[4] = {0.f, 0.f, 0.f, 0.f};

#pragma unroll 1
    for (int c = 0; c < 8; ++c) {
        const int row0 = blk * 1024 + wave * 256 + c * 32;
        s8 xfa = *(const s8*)&xbf[(size_t)(row0 + m) * 32 + 8 * q];
        s8 xfb = *(const s8*)&xbf[(size_t)(row0 + 16 + m) * 32 + 8 * q];
#pragma unroll
        for (int u = 0; u < 4; ++u) {
            // swapped operands: lane(q,m) reg r = h1[row0(+16)+4q+r][unit 16u+m]
            f4 ha = __builtin_amdgcn_mfma_f32_16x16x32_bf16(xfa, wgf[u], (f4){0.f,0.f,0.f,0.f}, 0, 0, 0);
            f4 hb = __builtin_amdgcn_mfma_f32_16x16x32_bf16(xfb, wgf[u], (f4){0.f,0.f,0.f,0.f}, 0, 0, 0);
            float g0 = gelu_f(ha[0] + bv[u]), g1 = gelu_f(ha[1] + bv[u]);
            float g2 = gelu_f(ha[2] + bv[u]), g3 = gelu_f(ha[3] + bv[u]);
            float e0 = gelu_f(hb[0] + bv[u]), e1 = gelu_f(hb[1] + bv[u]);
            float e2 = gelu_f(hb[2] + bv[u]), e3 = gelu_f(hb[3] + bv[u]);
            csum[u] += (g0 + g1 + g2 + g3) + (e0 + e1 + e2 + e3);
            i2 pa = (i2){bfpack(g0, g1), bfpack(g2, g3)};
            i2 pb = (i2){bfpack(e0, e1), bfpack(e2, e3)};
            *(i2*)&T[(16 * u + m) * 40 + 4 * q]      = pa;   // rows 4q..4q+3
            *(i2*)&T[(16 * u + m) * 40 + 16 + 4 * q] = pb;   // rows 16+4q..16+4q+3
        }
        // transposed fragments: lane(q,m) = T[16v+m][rows 8q..8q+7]
        // (in-wave LDS ordering only; T is wave-private, same pattern as old pass1)
        s8 fr0 = *(const s8*)&T[(m)*40      + 8 * q];
        s8 fr1 = *(const s8*)&T[(16 + m)*40 + 8 * q];
        s8 fr2 = *(const s8*)&T[(32 + m)*40 + 8 * q];
        s8 fr3 = *(const s8*)&T[(48 + m)*40 + 8 * q];
        gram[0] = __builtin_amdgcn_mfma_f32_16x16x32_bf16(fr0, fr0, gram[0], 0, 0, 0);
        gram[1] = __builtin_amdgcn_mfma_f32_16x16x32_bf16(fr0, fr1, gram[1], 0, 0, 0);
        gram[2] = __builtin_amdgcn_mfma_f32_16x16x32_bf16(fr0, fr2, gram[2], 0, 0, 0);
        gram[3] = __builtin_amdgcn_mfma_f32_16x16x32_bf16(fr0, fr3, gram[3], 0, 0, 0);
        gram[4] = __builtin_amdgcn_mfma_f32_16x16x32_bf16(fr1, fr1, gram[4], 0, 0, 0);
        gram[5] = __builtin_amdgcn_mfma_f32_16x16x32_bf16(fr1, fr2, gram[5], 0, 0, 0);
        gram[6] = __builtin_amdgcn_mfma_f32_16x16x32_bf16(fr1, fr3, gram[6], 0, 0, 0);
        gram[7] = __builtin_amdgcn_mfma_f32_16x16x32_bf16(fr2, fr2, gram[7], 0, 0, 0);
        gram[8] = __builtin_amdgcn_mfma_f32_16x16x32_bf16(fr2, fr3, gram[8], 0, 0, 0);
        gram[9] = __builtin_amdgcn_mfma_f32_16x16x32_bf16(fr3, fr3, gram[9], 0, 0, 0);
    }

    // col sums: rows are split across q only -> reduce over the 4 q-lanes
    float* colbuf = (float*)(smem + 20480);
#pragma unroll
    for (int u = 0; u < 4; ++u) {
        float s = csum[u];
        s += __shfl_xor(s, 16);
        s += __shfl_xor(s, 32);
        if (q == 0) colbuf[wave * 64 + u * 16 + m] = s;
    }
    __syncthreads();   // all waves done with T; gram bufs may alias it now
    float* gb = (float*)smem + (wave & 1) * 2560;
    if (wave < 2) {
#pragma unroll
        for (int p = 0; p < 10; ++p)
#pragma unroll
            for (int r = 0; r < 4; ++r)
                gb[p * 256 + (4 * q + r) * 16 + m] = gram[p][r];
    }
    __syncthreads();
    if (wave >= 2) {
#pragma unroll
        for (int p = 0; p < 10; ++p)
#pragma unroll
            for (int r = 0; r < 4; ++r)
                gb[p * 256 + (4 * q + r) * 16 + m] += gram[p][r];
    }
    __syncthreads();
    const float* g0b = (const float*)smem;
    const float* g1b = (const float*)smem + 2560;
    float* gp = ws + GRAMP_OFF + (size_t)(n * 32 + blk) * 2624;
    for (int i = tid; i < 2560; i += 256) gp[i] = g0b[i] + g1b[i];
    if (tid < 64)
        gp[2560 + tid] = colbuf[tid] + colbuf[64 + tid] + colbuf[128 + tid] + colbuf[192 + tid];
}

// ------ fold2: reduce Gram partials; analytic BN2 stats -> SUM2/SSQ2 -----
__global__ __launch_bounds__(256) void k_fold2(const float* __restrict__ W2,
                                               float* __restrict__ ws) {
    __shared__ float gsum[2624];
    __shared__ float Ca[4096];
    __shared__ float sW2f[4096];
    __shared__ float ma[64];
    const int n = blockIdx.x, t = threadIdx.x;

    for (int s = t; s < 2624; s += 256) {
        float a = 0.0f;
        const float* gp = ws + GRAMP_OFF + (size_t)n * 32 * 2624 + s;
#pragma unroll 8
        for (int b = 0; b < 32; ++b) a += gp[(size_t)b * 2624];
        gsum[s] = a;
    }
    // W2 rounded to bf16 precision so stats match the GEMM2 actually executed
    for (int i = t; i < 4096; i += 256)
        sW2f[i] = bf2f((short)f2bf(W2[(size_t)n * 4096 + i]));
    __syncthreads();
    if (t < 64) ma[t] = gsum[2560 + t] * (1.0f / 32768.0f);
    __syncthreads();
    // full 64x64 covariance from the 10 upper-tri 16x16 Gram blocks
    for (int idx = t; idx < 4096; idx += 256) {
        int i = idx >> 6, j = idx & 63;
        int v = i >> 4, w = j >> 4, ii = i & 15, jj = j & 15;
        float g = (v <= w)
            ? gsum[(v * 4 - ((v * (v + 1)) >> 1) + w) * 256 + ii * 16 + jj]
            : gsum[(w * 4 - ((w * (w + 1)) >> 1) + v) * 256 + jj * 16 + ii];
        Ca[idx] = g * (1.0f / 32768.0f) - ma[i] * ma[j];
    }
    __syncthreads();

    const int h = t >> 2, j4 = t & 3;   // quad per hidden unit
    f4 wreg[16];
#pragma unroll
    for (int j = 0; j < 16; ++j) wreg[j] = *(const f4*)&sW2f[h * 64 + 4 * j];
    float vp = 0.0f, mp = 0.0f;
#pragma unroll
    for (int k = 0; k < 16; ++k) {
        const int i = 16 * j4 + k;
        float inner = 0.0f;
        const f4* cr = (const f4*)&Ca[i * 64];
#pragma unroll
        for (int j = 0; j < 16; ++j) {
            f4 c = cr[j], w = wreg[j];
            inner = __builtin_fmaf(c[0], w[0],
                    __builtin_fmaf(c[1], w[1],
                    __builtin_fmaf(c[2], w[2],
                    __builtin_fmaf(c[3], w[3], inner))));
        }
        float wi = sW2f[h * 64 + i];
        vp = __builtin_fmaf(inner, wi, vp);
        mp = __builtin_fmaf(wi, ma[i], mp);
    }
    float var  = quad4_sum(vp);
    float mean = quad4_sum(mp);    // b2 omitted: cancels in BN shift
    if (j4 == 0) {
        ws[SUM2_OFF + n * 64 + h] = mean * 32768.0f;
        ws[SSQ2_OFF + n * 64 + h] = (var + mean * mean) * 32768.0f;
    }
}

// ------ pass 2 (full fused recompute): GEMM1+gelu+GEMM2+BN2+gelu+GEMM3 ---
__global__ __launch_bounds__(256, 4) void k_pass2r(const float* __restrict__ g2,
                                                   const float* __restrict__ be2,
                                                   const float* __restrict__ W3,
                                                   const float* __restrict__ b3,
                                                   float* __restrict__ ws,
                                                   float* __restrict__ out) {
    __shared__ __align__(16) short sW1[64 * 40];
    __shared__ __align__(16) short sW2[64 * 72];
    __shared__ __align__(16) short sA1[8 * 16 * 72];
    __shared__ float sSc[64], sSh[64], sW3v[64];

    const int n = blockIdx.x >> 7;
    const int blk = blockIdx.x & 127;
    const int tid = threadIdx.x;
    const int wave = tid >> 6;
    const int lane = tid & 63;
    const int m = lane & 15;
    const int q = lane >> 4;

    const short* bfbase = (const short*)(ws + BF_BASE_F);
    const short* w1g = bfbase + (size_t)n * 64 * 32;
    const short* w2g = bfbase + W2B_OFF_S + (size_t)n * 64 * 64;
    const short* xbf = bfbase + XBF_OFF_S;
    {
        int r = tid >> 2, c = tid & 3;
        *(s8*)&sW1[r * 40 + c * 8] = *(const s8*)&w1g[r * 32 + c * 8];
#pragma unroll
        for (int k = 0; k < 2; ++k) {
            int i2x = tid + k * 256;
            int r2 = i2x >> 3, c2 = i2x & 7;
            *(s8*)&sW2[r2 * 72 + c2 * 8] = *(const s8*)&w2g[r2 * 64 + c2 * 8];
        }
        if (tid < 64) {
            float mean = ws[SUM2_OFF + n * 64 + tid] * (1.0f / 32768.0f);
            float var  = ws[SSQ2_OFF + n * 64 + tid] * (1.0f / 32768.0f) - mean * mean;
            float sc = g2[n * 64 + tid] * rsqrtf(fmaxf(var, 0.0f) + BN_EPS);
            sSc[tid]  = sc;
            sSh[tid]  = be2[n * 64 + tid] - mean * sc;
            sW3v[tid] = W3[n * 64 + tid];
        }
    }
    __syncthreads();

    const float* bias1 = ws + BIAS1_OFF + n * 64;
    const float b3n = b3[n];
    short* myA1a = &sA1[(wave * 2 + 0) * 16 * 72];
    short* myA1b = &sA1[(wave * 2 + 1) * 16 * 72];

#pragma unroll
    for (int it = 0; it < 2; ++it) {
        const int row0 = blk * 256 + it * 128 + wave * 32;
        s8 xfa = *(const s8*)&xbf[(size_t)(row0 + m) * 32 + 8 * q];
        s8 xfb = *(const s8*)&xbf[(size_t)(row0 + 16 + m) * 32 + 8 * q];

        f4 acc1a[4], acc1b[4];
#pragma unroll
        for (int t = 0; t < 4; ++t) {
            s8 wf = *(const s8*)&sW1[(16 * t + m) * 40 + q * 8];
            acc1a[t] = __builtin_amdgcn_mfma_f32_16x16x32_bf16(wf, xfa, (f4){0.f, 0.f, 0.f, 0.f}, 0, 0, 0);
            acc1b[t] = __builtin_amdgcn_mfma_f32_16x16x32_bf16(wf, xfb, (f4){0.f, 0.f, 0.f, 0.f}, 0, 0, 0);
        }
#pragma unroll
        for (int t = 0; t < 4; ++t) {
            f4 bv = *(const f4*)&bias1[16 * t + 4 * q];
            s4 pa, pb;
#pragma unroll
            for (int r = 0; r < 4; ++r) {
                pa[r] = (short)f2bf(gelu_f(acc1a[t][r] + bv[r]));
                pb[r] = (short)f2bf(gelu_f(acc1b[t][r] + bv[r]));
            }
            *(s4*)&myA1a[m * 72 + 16 * t + 4 * q] = pa;
            *(s4*)&myA1b[m * 72 + 16 * t + 4 * q] = pb;
        }
        s8 af0a = *(const s8*)&myA1a[m * 72 + 8 * q];
        s8 af1a = *(const s8*)&myA1a[m * 72 + 32 + 8 * q];
        s8 af0b = *(const s8*)&myA1b[m * 72 + 8 * q];
        s8 af1b = *(const s8*)&myA1b[m * 72 + 32 + 8 * q];
        float pa = 0.0f, pb = 0.0f;
#pragma unroll
        for (int u = 0; u < 4; ++u) {
            s8 w0 = *(const s8*)&sW2[(16 * u + m) * 72 + 8 * q];
            s8 w1 = *(const s8*)&sW2[(16 * u + m) * 72 + 32 + 8 * q];
            f4 aa = (f4){0.f, 0.f, 0.f, 0.f};
            f4 ab = (f4){0.f, 0.f, 0.f, 0.f};
            aa = __builtin_amdgcn_mfma_f32_16x16x32_bf16(w0, af0a, aa, 0, 0, 0);
            ab = __builtin_amdgcn_mfma_f32_16x16x32_bf16(w0, af0b, ab, 0, 0, 0);
            aa = __builtin_amdgcn_mfma_f32_16x16x32_bf16(w1, af1a, aa, 0, 0, 0);
            ab = __builtin_amdgcn_mfma_f32_16x16x32_bf16(w1, af1b, ab, 0, 0, 0);
            f4 scv = *(const f4*)&sSc[16 * u + 4 * q];
            f4 shv = *(const f4*)&sSh[16 * u + 4 * q];
            f4 w3v = *(const f4*)&sW3v[16 * u + 4 * q];
#pragma unroll
            for (int r = 0; r < 4; ++r) {
                float va = __builtin_fmaf(aa[r], scv[r], shv[r]);
                float vb = __builtin_fmaf(ab[r], scv[r], shv[r]);
                pa = __builtin_fmaf(gelu_f(va), w3v[r], pa);
                pb = __builtin_fmaf(gelu_f(vb), w3v[r], pb);
            }
        }
        pa += __shfl_xor(pa, 16);  pa += __shfl_xor(pa, 32);
        pb += __shfl_xor(pb, 16);  pb += __shfl_xor(pb, 32);
        if (q == 0) {
            out[(size_t)(row0 + m) * 28 + n]      = pa + b3n;
            out[(size_t)(row0 + 16 + m) * 28 + n] = pb + b3n;
        }
    }
}

extern "C" void kernel_launch(void* const* d_in, const int* in_sizes, int n_in,
                              void* d_out, int out_size, void* d_ws, size_t ws_size,
                              hipStream_t stream) {
    const float* X   = (const float*)d_in[0];
    const float* Wl  = (const float*)d_in[1];
    const float* W1  = (const float*)d_in[2];
    const float* g1  = (const float*)d_in[4];
    const float* be1 = (const float*)d_in[5];
    const float* W2  = (const float*)d_in[6];
    const float* g2  = (const float*)d_in[8];
    const float* be2 = (const float*)d_in[9];
    const float* W3  = (const float*)d_in[10];
    const float* b3  = (const float*)d_in[11];
    float* out = (float*)d_out;
    float* ws  = (float*)d_ws;

    k_xstats<<<dim3(256), dim3(256), 0, stream>>>(X, ws);
    k_fold1<<<dim3(28), dim3(256), 0, stream>>>(Wl, W1, g1, be1, W2, ws, out + 917504);
    k_agram<<<dim3(28 * 32), dim3(256), 0, stream>>>(ws);
    k_fold2<<<dim3(28), dim3(256), 0, stream>>>(W2, ws);
    k_pass2r<<<dim3(28 * 128), dim3(256), 0, stream>>>(g2, be2, W3, b3, ws, out);
}